// Round 5
// baseline (14643.648 us; speedup 1.0000x reference)
//
#include <hip/hip_runtime.h>
#include <hip/hip_bf16.h>

// ---------------------------------------------------------------------------
// SimpleCNN / TRM forward. Round 12 = occupancy doubling. r7..r11 showed NO
// compute-phase or barrier-mechanism micro-edit moves the 25us step (rings,
// pins, chain splits, sense-reversing barrier: all neutral). Remaining model:
// A-operand loads are L2-LATENCY-bound at 2 waves/SIMD (Occupancy 24%) —
// not enough TLP to overlap the VMEM stream with LDS+MFMA. Fix: 1024-thread
// blocks (16 waves, 4/SIMD), same grid 256 (1 block/CU):
//   wave pair (w, w+8) shares a 16-row tile:
//   GEMM1 split by N: lo wave cols [c1,c1+16), hi wave [c1+16,c1+32), full K.
//   GEMM2 split by K: lo K[0,512), hi K[512,1024); hi -> LDS scratch,
//   __syncthreads, lo adds + epilogue.
// Same per-block MFMA/LDS totals. r7 barrier verbatim. LDS 136KB -> 1 blk/CU.
// Math identical: split-bf16 MFMA, fp32 prologue.
// ---------------------------------------------------------------------------

typedef unsigned short ushort_t;
typedef __attribute__((ext_vector_type(8))) short short8;
typedef __attribute__((ext_vector_type(4))) float f32x4;

__device__ inline unsigned f2bf_rne(float v) {
    unsigned u = __float_as_uint(v);
    return (u + 0x7fffu + ((u >> 16) & 1u)) >> 16;
}
__device__ inline void split2(float v, ushort_t& h, ushort_t& l) {
    unsigned uh = f2bf_rne(v);
    h = (ushort_t)uh;
    float fh = __uint_as_float(uh << 16);
    l = (ushort_t)f2bf_rne(v - fh);
}

// ---------------- conv1 (1->16, 3x3 SAME, 28x28) + relu + maxpool2 ----------
__global__ __launch_bounds__(256) void conv1_pool(
    const float* __restrict__ in, const float* __restrict__ w,
    const float* __restrict__ bias, float* __restrict__ out)
{
    int idx = blockIdx.x * 256 + threadIdx.x;   // 1024*16*14*14
    int xo = idx % 14; int t = idx / 14;
    int yo = t % 14;  t /= 14;
    int oc = t % 16;  int b = t / 16;
    const float* ip = in + (size_t)b * 784;
    const float* wp = w + oc * 9;
    float win[4][4];
#pragma unroll
    for (int yy = 0; yy < 4; ++yy)
#pragma unroll
        for (int xx = 0; xx < 4; ++xx) {
            int y = 2 * yo + yy - 1, x = 2 * xo + xx - 1;
            win[yy][xx] = (y >= 0 && y < 28 && x >= 0 && x < 28) ? ip[y * 28 + x] : 0.f;
        }
    float bs = bias[oc];
    float m = -1e30f;
#pragma unroll
    for (int py = 0; py < 2; ++py)
#pragma unroll
        for (int px = 0; px < 2; ++px) {
            float s = bs;
#pragma unroll
            for (int dy = 0; dy < 3; ++dy)
#pragma unroll
                for (int dx = 0; dx < 3; ++dx)
                    s = fmaf(win[py + dy][px + dx], wp[dy * 3 + dx], s);
            m = fmaxf(m, s);
        }
    out[idx] = fmaxf(m, 0.f);
}

// ---------------- conv2 (16->32, 3x3 SAME, 14x14) + relu + maxpool2 ---------
__global__ __launch_bounds__(256) void conv2_pool(
    const float* __restrict__ in, const float* __restrict__ w,
    const float* __restrict__ bias, float* __restrict__ out)
{
    __shared__ float ws_[32 * 16 * 9];
    for (int i = threadIdx.x; i < 4608; i += 256) ws_[i] = w[i];
    __syncthreads();
    int idx = blockIdx.x * 256 + threadIdx.x;   // 1024*32*7*7
    int xo = idx % 7; int t = idx / 7;
    int yo = t % 7;  t /= 7;
    int oc = t % 32; int b = t / 32;
    const float* ip = in + (size_t)b * 16 * 196;
    float bs = bias[oc];
    float s00 = bs, s01 = bs, s10 = bs, s11 = bs;
    for (int ic = 0; ic < 16; ++ic) {
        const float* ipp = ip + ic * 196;
        float win[4][4];
#pragma unroll
        for (int yy = 0; yy < 4; ++yy)
#pragma unroll
            for (int xx = 0; xx < 4; ++xx) {
                int y = 2 * yo + yy - 1, x = 2 * xo + xx - 1;
                win[yy][xx] = (y >= 0 && y < 14 && x >= 0 && x < 14) ? ipp[y * 14 + x] : 0.f;
            }
        const float* wp = ws_ + (oc * 16 + ic) * 9;
#pragma unroll
        for (int dy = 0; dy < 3; ++dy)
#pragma unroll
            for (int dx = 0; dx < 3; ++dx) {
                float wv = wp[dy * 3 + dx];
                s00 = fmaf(win[0 + dy][0 + dx], wv, s00);
                s01 = fmaf(win[0 + dy][1 + dx], wv, s01);
                s10 = fmaf(win[1 + dy][0 + dx], wv, s10);
                s11 = fmaf(win[1 + dy][1 + dx], wv, s11);
            }
    }
    float m = fmaxf(fmaxf(s00, s01), fmaxf(s10, s11));
    out[idx] = fmaxf(m, 0.f);
}

// ---------------- fp32 tiled GEMM (prologue only: proj1, proj2) -------------
#define BMF 64
#define BNF 64
#define BKF 16

__global__ __launch_bounds__(256) void gemm_f32(
    const float* __restrict__ A0, const float* __restrict__ W,
    const float* __restrict__ bias, float* __restrict__ C,
    int M, int N, int K)
{
    __shared__ float As[BKF][BMF];
    __shared__ float Bs[BKF][BNF];
    const int tid = threadIdx.x;
    const int tx = tid % 16;
    const int ty = tid / 16;
    const int row0 = blockIdx.y * BMF;
    const int col0 = blockIdx.x * BNF;
    float acc[4][4] = {};
    const int ra = tid / 4;
    const int ca = 4 * (tid % 4);
    const int rb = tid / 16;
    const int cb = 4 * (tid % 16);
    for (int k0 = 0; k0 < K; k0 += BKF) {
        float4 v = *(const float4*)(A0 + (size_t)(row0 + ra) * K + k0 + ca);
        float4 bvec = *(const float4*)(W + (size_t)(k0 + rb) * N + col0 + cb);
        As[ca + 0][ra] = v.x;
        As[ca + 1][ra] = v.y;
        As[ca + 2][ra] = v.z;
        As[ca + 3][ra] = v.w;
        *(float4*)&Bs[rb][cb] = bvec;
        __syncthreads();
#pragma unroll
        for (int kk = 0; kk < BKF; ++kk) {
            float4 av = *(const float4*)&As[kk][ty * 4];
            float4 bv = *(const float4*)&Bs[kk][tx * 4];
            float a_[4] = {av.x, av.y, av.z, av.w};
            float b_[4] = {bv.x, bv.y, bv.z, bv.w};
#pragma unroll
            for (int i = 0; i < 4; ++i)
#pragma unroll
                for (int j = 0; j < 4; ++j)
                    acc[i][j] = fmaf(a_[i], b_[j], acc[i][j]);
        }
        __syncthreads();
    }
    float4 bv = *(const float4*)(bias + col0 + tx * 4);
    float bb[4] = {bv.x, bv.y, bv.z, bv.w};
#pragma unroll
    for (int i = 0; i < 4; ++i) {
        float4 o;
        o.x = fmaxf(acc[i][0] + bb[0], 0.f);
        o.y = fmaxf(acc[i][1] + bb[1], 0.f);
        o.z = fmaxf(acc[i][2] + bb[2], 0.f);
        o.w = fmaxf(acc[i][3] + bb[3], 0.f);
        *(float4*)(C + (size_t)(row0 + ty * 4 + i) * N + col0 + tx * 4) = o;
    }
}

// ---------------- weight prep: transpose + split ----------------------------
__global__ __launch_bounds__(256) void prep_wt(
    const float* __restrict__ w, ushort_t* __restrict__ th,
    ushort_t* __restrict__ tl, int K, int N)
{
    int idx = blockIdx.x * 256 + threadIdx.x;   // n*K + k
    int n = idx / K, k = idx % K;
    float v = w[(size_t)k * N + n];
    split2(v, th[idx], tl[idx]);
}

// ---------------- init: io = inp + out_e ; xs = split(io + lat_e) -----------
__global__ __launch_bounds__(256) void init_xs(
    const float* __restrict__ inpf, const float* __restrict__ oute,
    const float* __restrict__ late, float* __restrict__ io,
    ushort_t* __restrict__ xh, ushort_t* __restrict__ xl)
{
    int i = blockIdx.x * 256 + threadIdx.x;     // 1024*512
    float t = inpf[i] + oute[i];
    io[i] = t;
    split2(t + late[i], xh[i], xl[i]);
}

// ---------------- barrier init ---------------------------------------------
__global__ void init_bar(unsigned* bar) {
    bar[threadIdx.x] = 0;          // [0..255]: group barrier counters (g*32)
    bar[threadIdx.x + 256] = 0;    // [384+x*8]: XCD slot-claim counters
}

// ---------------------------------------------------------------------------
// Per-XCD-group (32-block) barrier — r7 structure verbatim (proven fastest).
// ---------------------------------------------------------------------------
__device__ __forceinline__ void group_barrier(unsigned* bar, int g,
                                              unsigned& tgt)
{
    __syncthreads();
    if (threadIdx.x == 0) {
        __builtin_amdgcn_fence(__ATOMIC_RELEASE, "workgroup");
        __hip_atomic_fetch_add(bar + g * 32, 1u, __ATOMIC_RELAXED,
                               __HIP_MEMORY_SCOPE_AGENT);
        while (__hip_atomic_load(bar + g * 32, __ATOMIC_RELAXED,
                                 __HIP_MEMORY_SCOPE_AGENT) < tgt)
            __builtin_amdgcn_s_sleep(1);
        __builtin_amdgcn_fence(__ATOMIC_ACQUIRE, "workgroup");
        asm volatile("buffer_inv sc0" ::: "memory");   // vector L1 inv only
    }
    tgt += 32;
    __syncthreads();
}

// A-operand fragment load from global (MFMA 16x16x32 A layout:
// lane (li,q) holds A[row][q*8..q*8+8) at kpos offset).
__device__ __forceinline__ short8 afrag(const ushort_t* __restrict__ p,
                                        int row, int K, int kpos)
{
    return *(const short8*)(p + (size_t)row * K + kpos);
}

// ---------------------------------------------------------------------------
// Persistent TRM kernel. grid 256, 1024 threads (16 waves, 4/SIMD), 1 blk/CU
// (136KB LDS). Block self-assigns (g = physical XCD, slot = claim 0..31).
// Group g owns rows [g*128, g*128+128). Wave pair (w, w+8), w in [0,8),
// shares row tile rowA = g*128 + w*16:
//   GEMM1 (N-split): lo wave -> cols [c1, c1+16), hi wave -> [c1+16, c1+32),
//                    both full K=512. Independent accs, independent epilogue.
//   GEMM2 (K-split): lo wave K [0,512), hi wave K [512,1024). hi writes its
//                    f32x4 partial to LDS scratch; __syncthreads; lo adds and
//                    runs the recursion-state epilogue.
// LDS weights in MFMA fragment order (as r7): every ds_read_b128 is a
// wave-contiguous 1KB. A-prefetch: ring-8, consume-then-prefetch, pinned.
// ---------------------------------------------------------------------------
__global__ __launch_bounds__(1024, 4) void trm_persist(
    ushort_t* __restrict__ xs_hi, ushort_t* __restrict__ xs_lo,
    ushort_t* __restrict__ h1_hi, ushort_t* __restrict__ h1_lo,
    const ushort_t* __restrict__ W1h, const ushort_t* __restrict__ W1l,
    const ushort_t* __restrict__ W2h, const ushort_t* __restrict__ W2l,
    const float* __restrict__ bb1, const float* __restrict__ bb2,
    float* __restrict__ io, const float* __restrict__ inpf,
    float* __restrict__ latf, float* __restrict__ outf,
    const float* __restrict__ hw, const float* __restrict__ hb,
    float* __restrict__ logits, unsigned* bar)
{
    __shared__ __align__(16) unsigned char w1lds[65536];
    __shared__ __align__(16) unsigned char w2lds[65536];
    __shared__ __align__(16) f32x4 scr[512];     // 8KB GEMM2 partial exchange
    __shared__ int sh_gs;

    const int tid = threadIdx.x;
    const int w = tid >> 6, lane = tid & 63;
    const int q = lane >> 4, li = lane & 15;
    const int rw = w & 7;                 // row-tile index (pairs share)
    const int hi_half = w >> 3;           // 0 = lo wave, 1 = hi wave

    // ---- self-organize: group by PHYSICAL XCD, claim slot ----
    if (tid == 0) {
        unsigned xcc;
        asm volatile("s_getreg_b32 %0, hwreg(HW_REG_XCC_ID)" : "=s"(xcc));
        xcc &= 7u;
        unsigned s = __hip_atomic_fetch_add(bar + 384 + xcc * 8, 1u,
                                            __ATOMIC_RELAXED,
                                            __HIP_MEMORY_SCOPE_AGENT);
        sh_gs = (int)((xcc << 8) | (s & 31u));
    }
    __syncthreads();
    const int g = sh_gs >> 8;
    const int slot = sh_gs & 255;
    const int c1 = slot * 32;       // GEMM1 col base
    const int c2 = slot * 16;       // GEMM2 col base
    const int rowA = g * 128 + rw * 16;

    // ---- preload weight slices into LDS in fragment order (once) ----
    for (int i = tid; i < 4096; i += 1024) {              // W1: 2*32n*64c
        int comp = i >> 11;
        int rem = i & 2047;
        int n = rem >> 6, c = rem & 63;                   // n 0..31, c 0..63
        const ushort_t* src = (comp ? W1l : W1h) + (size_t)(c1 + n) * 512 + c * 8;
        int dst = ((((comp << 4) + (c >> 2)) * 2 + (n >> 4)) * 64 +
                   ((c & 3) * 16 + (n & 15))) * 16;
        *(uint4*)(w1lds + dst) = *(const uint4*)src;
    }
    for (int i = tid; i < 4096; i += 1024) {              // W2: 2*16n*128c
        int comp = i >> 11;
        int rem = i & 2047;
        int n = rem >> 7, c = rem & 127;                  // n 0..15, c 0..127
        const ushort_t* src = (comp ? W2l : W2h) + (size_t)(c2 + n) * 1024 + c * 8;
        int dst = (((comp << 5) + (c >> 2)) * 64 + ((c & 3) * 16 + n)) * 16;
        *(uint4*)(w2lds + dst) = *(const uint4*)src;
    }
    __syncthreads();

    // per-wave GEMM1 bias (its own 16-col tile) and GEMM2 bias (lo only)
    float bias1v = bb1[c1 + hi_half * 16 + li];
    float bias2 = bb2[c2 + li];
    unsigned tgt = 32;

    for (int step = 0; step < 336; ++step) {              // 48 sup * 7
        // ==== GEMM1: h1[16r x 32c] = relu(xs @ W1 + bb1); N-split pair ====
        {
            f32x4 acc = {};
            short8 aF[8][2];                              // ring [slot][comp]
#pragma unroll
            for (int p = 0; p < 8; ++p) {
                int kp = p * 32 + q * 8;
                aF[p][0] = afrag(xs_hi, rowA + li, 512, kp);
                aF[p][1] = afrag(xs_lo, rowA + li, 512, kp);
            }
            __builtin_amdgcn_sched_barrier(0);            // pin prologue loads
            const int tjoff = hi_half * 1024;             // B-tile byte offset
#pragma unroll
            for (int s = 0; s < 16; ++s) {
                short8 ah = aF[s & 7][0], al = aF[s & 7][1];   // consume first
                if (s + 8 < 16) {
                    int kp = (s + 8) * 32 + q * 8;
                    aF[(s + 8) & 7][0] = afrag(xs_hi, rowA + li, 512, kp);
                    aF[(s + 8) & 7][1] = afrag(xs_lo, rowA + li, 512, kp);
                }
                __builtin_amdgcn_sched_barrier(0);        // pin prefetch issue
                const int base = (s * 2 * 64 + lane) * 16 + tjoff;
                short8 bh = *(const short8*)(w1lds + base);
                short8 bl = *(const short8*)(w1lds + 32768 + base);
                acc = __builtin_amdgcn_mfma_f32_16x16x32_bf16(ah, bh, acc, 0, 0, 0);
                acc = __builtin_amdgcn_mfma_f32_16x16x32_bf16(ah, bl, acc, 0, 0, 0);
                acc = __builtin_amdgcn_mfma_f32_16x16x32_bf16(al, bh, acc, 0, 0, 0);
                acc = __builtin_amdgcn_mfma_f32_16x16x32_bf16(al, bl, acc, 0, 0, 0);
            }
            // epilogue: each wave writes its own 16-col tile
            int colg = c1 + hi_half * 16 + li;
#pragma unroll
            for (int rr = 0; rr < 4; ++rr) {
                int rowg = rowA + q * 4 + rr;
                size_t idx = (size_t)rowg * 1024 + colg;
                float v = fmaxf(acc[rr] + bias1v, 0.f);
                split2(v, h1_hi[idx], h1_lo[idx]);
            }
        }
        group_barrier(bar, g, tgt);

        // ==== GEMM2: xs'[16r x 16c] = f(relu(h1 @ W2 + bb2)); K-split ====
        {
            int im = step % 7;
            int mode = (im < 5) ? 1 : ((im == 5) ? 2 : 3);
            f32x4 acc = {};
            short8 aF[8][2];
            const int sb = hi_half * 16;                  // K-half s-base
#pragma unroll
            for (int p = 0; p < 8; ++p) {
                int kp = (sb + p) * 32 + q * 8;
                aF[p][0] = afrag(h1_hi, rowA + li, 1024, kp);
                aF[p][1] = afrag(h1_lo, rowA + li, 1024, kp);
            }
            __builtin_amdgcn_sched_barrier(0);            // pin prologue loads
#pragma unroll
            for (int s = 0; s < 16; ++s) {
                short8 ah = aF[s & 7][0], al = aF[s & 7][1];   // consume first
                if (s + 8 < 16) {
                    int kp = (sb + s + 8) * 32 + q * 8;
                    aF[(s + 8) & 7][0] = afrag(h1_hi, rowA + li, 1024, kp);
                    aF[(s + 8) & 7][1] = afrag(h1_lo, rowA + li, 1024, kp);
                }
                __builtin_amdgcn_sched_barrier(0);        // pin prefetch issue
                const int base = ((sb + s) * 64 + lane) * 16;
                short8 bh = *(const short8*)(w2lds + base);
                short8 bl = *(const short8*)(w2lds + 32768 + base);
                acc = __builtin_amdgcn_mfma_f32_16x16x32_bf16(ah, bh, acc, 0, 0, 0);
                acc = __builtin_amdgcn_mfma_f32_16x16x32_bf16(ah, bl, acc, 0, 0, 0);
                acc = __builtin_amdgcn_mfma_f32_16x16x32_bf16(al, bh, acc, 0, 0, 0);
                acc = __builtin_amdgcn_mfma_f32_16x16x32_bf16(al, bl, acc, 0, 0, 0);
            }
            // K-split reduction: hi half deposits partial, lo half finishes
            if (hi_half) scr[rw * 64 + lane] = acc;
            __syncthreads();
            if (!hi_half) {
                acc += scr[rw * 64 + lane];
                int colg = c2 + li;
#pragma unroll
                for (int rr = 0; rr < 4; ++rr) {
                    int rowg = rowA + q * 4 + rr;
                    size_t idx = (size_t)rowg * 512 + colg;
                    float v = fmaxf(acc[rr] + bias2, 0.f);
                    if (mode == 1) {
                        split2(io[idx] + v, xs_hi[idx], xs_lo[idx]);
                    } else if (mode == 2) {
                        split2(inpf[idx] + v, xs_hi[idx], xs_lo[idx]);
                        latf[idx] = v;
                    } else {
                        outf[idx] = v;
                        float t2 = inpf[idx] + v;
                        io[idx] = t2;
                        split2(t2 + latf[idx], xs_hi[idx], xs_lo[idx]);
                    }
                }
            }
        }
        group_barrier(bar, g, tgt);
    }

    // ---- head: logits rows [g*128, g*128+128), 1280 elems per group ----
    // (last loop iteration ended with a full group barrier; outf is visible)
    {
        int idx = slot * 1024 + tid;
        if (idx < 1280) {
            int rloc = idx / 10, j = idx % 10;
            int row = g * 128 + rloc;
            const float* r = outf + (size_t)row * 512;
            float s = hb[j];
            for (int k = 0; k < 512; ++k) s = fmaf(r[k], hw[k * 10 + j], s);
            logits[row * 10 + j] = s;
        }
    }
}

extern "C" void kernel_launch(void* const* d_in, const int* in_sizes, int n_in,
                              void* d_out, int out_size, void* d_ws, size_t ws_size,
                              hipStream_t stream)
{
    const float* raw   = (const float*)d_in[0];
    const float* out_e = (const float*)d_in[1];
    const float* lat_e = (const float*)d_in[2];
    const float* c1w = (const float*)d_in[3];
    const float* c1b = (const float*)d_in[4];
    const float* c2w = (const float*)d_in[5];
    const float* c2b = (const float*)d_in[6];
    const float* pw1 = (const float*)d_in[7];
    const float* pb1 = (const float*)d_in[8];
    const float* pw2 = (const float*)d_in[9];
    const float* pb2 = (const float*)d_in[10];
    const float* bw1 = (const float*)d_in[11];
    const float* bb1 = (const float*)d_in[12];
    const float* bw2 = (const float*)d_in[13];
    const float* bb2 = (const float*)d_in[14];
    const float* hw  = (const float*)d_in[15];
    const float* hb  = (const float*)d_in[16];
    // d_in[17]=Nsup(16), d_in[18]=n_latent(6): fixed, hard-coded.

    char* base = (char*)d_ws;
    float*    pool1  = (float*)   (base + 0);          // conv1 out (pre-backbone)
    ushort_t* h1_hi  = (ushort_t*)(base + 0);
    ushort_t* h1_lo  = (ushort_t*)(base + 2097152);
    ushort_t* xs_hi  = (ushort_t*)(base + 4194304);
    ushort_t* xs_lo  = (ushort_t*)(base + 5242880);
    float*    io     = (float*)   (base + 6291456);
    float*    latf   = (float*)   (base + 8388608);
    float*    h1f    = (float*)   (base + 0);          // proj1 out (pre-backbone)
    float*    h      = (float*)   (base + 12845056);   // conv2 out fp32
    float*    inpf   = (float*)   (base + 19267584);
    float*    outf   = (float*)   (base + 21364736);
    ushort_t* bW1t_h = (ushort_t*)(base + 23461888);   // [1024n][512k]
    ushort_t* bW1t_l = (ushort_t*)(base + 24510464);
    ushort_t* bW2t_h = (ushort_t*)(base + 25559040);   // [512n][1024k]
    ushort_t* bW2t_l = (ushort_t*)(base + 26607616);
    unsigned* bar    = (unsigned*)(base + 27656192);   // 2KB barrier/claim

    // weight prep (every launch; ws is re-poisoned by harness)
    prep_wt<<<2048, 256, 0, stream>>>(bw1, bW1t_h, bW1t_l, 512, 1024);
    prep_wt<<<2048, 256, 0, stream>>>(bw2, bW2t_h, bW2t_l, 1024, 512);

    // fp32 prologue
    conv1_pool<<<3211264 / 256, 256, 0, stream>>>(raw, c1w, c1b, pool1);
    conv2_pool<<<1605632 / 256, 256, 0, stream>>>(pool1, c2w, c2b, h);
    gemm_f32<<<dim3(16, 16), 256, 0, stream>>>(h, pw1, pb1, h1f, 1024, 1024, 1568);
    gemm_f32<<<dim3(8, 16), 256, 0, stream>>>(h1f, pw2, pb2, inpf, 1024, 512, 1024);
    init_xs<<<2048, 256, 0, stream>>>(inpf, out_e, lat_e, io, xs_hi, xs_lo);

    // barrier init (bar region untouched by the prologue; launched last)
    init_bar<<<1, 256, 0, stream>>>(bar);

    // the whole recursion + head in ONE persistent kernel
    trm_persist<<<256, 1024, 0, stream>>>(
        xs_hi, xs_lo, h1_hi, h1_lo, bW1t_h, bW1t_l, bW2t_h, bW2t_l,
        bb1, bb2, io, inpf, latf, outf, hw, hb, (float*)d_out, bar);
}

// Round 6
// 10860.442 us; speedup vs baseline: 1.3483x; 1.3483x over previous
//
#include <hip/hip_runtime.h>
#include <hip/hip_bf16.h>

// ---------------------------------------------------------------------------
// SimpleCNN / TRM forward. Round 13 = the CLEAN occupancy test.
// r12 failed because __launch_bounds__(1024,4) (min-BLOCKS semantics) forced
// a 64-VGPR cap -> the depth-8 rings spilled to scratch -> 15.7 GB of HBM
// traffic (FETCH_SIZE tell-tale) at 1.1 TB/s. Occupancy DID reach 48%.
// This round: same 16-wave pair-split structure, but
//   (1) __launch_bounds__(1024, 1): 1 block/CU min -> compiler must fit 16
//       waves -> VGPR cap 128 (4 waves/SIMD x 128 = 512 pool), no spills.
//   (2) ring depth 2 (16 VGPR) — latency hiding delegated to TLP (the
//       hypothesis under test: 4 waves/SIMD covers L2 latency that 2 cannot).
//   (3) no sched_barrier pins (compiler schedules freely).
// Wave pair (w, w+8) shares a 16-row tile: GEMM1 split by N (lo cols
// [c1,c1+16), hi [c1+16,c1+32), full K); GEMM2 split by K (lo [0,512),
// hi [512,1024), hi -> LDS scr, __syncthreads, lo adds + epilogue).
// r7 group barrier verbatim. Math identical: split-bf16 MFMA, fp32 prologue.
// ---------------------------------------------------------------------------

typedef unsigned short ushort_t;
typedef __attribute__((ext_vector_type(8))) short short8;
typedef __attribute__((ext_vector_type(4))) float f32x4;

__device__ inline unsigned f2bf_rne(float v) {
    unsigned u = __float_as_uint(v);
    return (u + 0x7fffu + ((u >> 16) & 1u)) >> 16;
}
__device__ inline void split2(float v, ushort_t& h, ushort_t& l) {
    unsigned uh = f2bf_rne(v);
    h = (ushort_t)uh;
    float fh = __uint_as_float(uh << 16);
    l = (ushort_t)f2bf_rne(v - fh);
}

// ---------------- conv1 (1->16, 3x3 SAME, 28x28) + relu + maxpool2 ----------
__global__ __launch_bounds__(256) void conv1_pool(
    const float* __restrict__ in, const float* __restrict__ w,
    const float* __restrict__ bias, float* __restrict__ out)
{
    int idx = blockIdx.x * 256 + threadIdx.x;   // 1024*16*14*14
    int xo = idx % 14; int t = idx / 14;
    int yo = t % 14;  t /= 14;
    int oc = t % 16;  int b = t / 16;
    const float* ip = in + (size_t)b * 784;
    const float* wp = w + oc * 9;
    float win[4][4];
#pragma unroll
    for (int yy = 0; yy < 4; ++yy)
#pragma unroll
        for (int xx = 0; xx < 4; ++xx) {
            int y = 2 * yo + yy - 1, x = 2 * xo + xx - 1;
            win[yy][xx] = (y >= 0 && y < 28 && x >= 0 && x < 28) ? ip[y * 28 + x] : 0.f;
        }
    float bs = bias[oc];
    float m = -1e30f;
#pragma unroll
    for (int py = 0; py < 2; ++py)
#pragma unroll
        for (int px = 0; px < 2; ++px) {
            float s = bs;
#pragma unroll
            for (int dy = 0; dy < 3; ++dy)
#pragma unroll
                for (int dx = 0; dx < 3; ++dx)
                    s = fmaf(win[py + dy][px + dx], wp[dy * 3 + dx], s);
            m = fmaxf(m, s);
        }
    out[idx] = fmaxf(m, 0.f);
}

// ---------------- conv2 (16->32, 3x3 SAME, 14x14) + relu + maxpool2 ---------
__global__ __launch_bounds__(256) void conv2_pool(
    const float* __restrict__ in, const float* __restrict__ w,
    const float* __restrict__ bias, float* __restrict__ out)
{
    __shared__ float ws_[32 * 16 * 9];
    for (int i = threadIdx.x; i < 4608; i += 256) ws_[i] = w[i];
    __syncthreads();
    int idx = blockIdx.x * 256 + threadIdx.x;   // 1024*32*7*7
    int xo = idx % 7; int t = idx / 7;
    int yo = t % 7;  t /= 7;
    int oc = t % 32; int b = t / 32;
    const float* ip = in + (size_t)b * 16 * 196;
    float bs = bias[oc];
    float s00 = bs, s01 = bs, s10 = bs, s11 = bs;
    for (int ic = 0; ic < 16; ++ic) {
        const float* ipp = ip + ic * 196;
        float win[4][4];
#pragma unroll
        for (int yy = 0; yy < 4; ++yy)
#pragma unroll
            for (int xx = 0; xx < 4; ++xx) {
                int y = 2 * yo + yy - 1, x = 2 * xo + xx - 1;
                win[yy][xx] = (y >= 0 && y < 14 && x >= 0 && x < 14) ? ipp[y * 14 + x] : 0.f;
            }
        const float* wp = ws_ + (oc * 16 + ic) * 9;
#pragma unroll
        for (int dy = 0; dy < 3; ++dy)
#pragma unroll
            for (int dx = 0; dx < 3; ++dx) {
                float wv = wp[dy * 3 + dx];
                s00 = fmaf(win[0 + dy][0 + dx], wv, s00);
                s01 = fmaf(win[0 + dy][1 + dx], wv, s01);
                s10 = fmaf(win[1 + dy][0 + dx], wv, s10);
                s11 = fmaf(win[1 + dy][1 + dx], wv, s11);
            }
    }
    float m = fmaxf(fmaxf(s00, s01), fmaxf(s10, s11));
    out[idx] = fmaxf(m, 0.f);
}

// ---------------- fp32 tiled GEMM (prologue only: proj1, proj2) -------------
#define BMF 64
#define BNF 64
#define BKF 16

__global__ __launch_bounds__(256) void gemm_f32(
    const float* __restrict__ A0, const float* __restrict__ W,
    const float* __restrict__ bias, float* __restrict__ C,
    int M, int N, int K)
{
    __shared__ float As[BKF][BMF];
    __shared__ float Bs[BKF][BNF];
    const int tid = threadIdx.x;
    const int tx = tid % 16;
    const int ty = tid / 16;
    const int row0 = blockIdx.y * BMF;
    const int col0 = blockIdx.x * BNF;
    float acc[4][4] = {};
    const int ra = tid / 4;
    const int ca = 4 * (tid % 4);
    const int rb = tid / 16;
    const int cb = 4 * (tid % 16);
    for (int k0 = 0; k0 < K; k0 += BKF) {
        float4 v = *(const float4*)(A0 + (size_t)(row0 + ra) * K + k0 + ca);
        float4 bvec = *(const float4*)(W + (size_t)(k0 + rb) * N + col0 + cb);
        As[ca + 0][ra] = v.x;
        As[ca + 1][ra] = v.y;
        As[ca + 2][ra] = v.z;
        As[ca + 3][ra] = v.w;
        *(float4*)&Bs[rb][cb] = bvec;
        __syncthreads();
#pragma unroll
        for (int kk = 0; kk < BKF; ++kk) {
            float4 av = *(const float4*)&As[kk][ty * 4];
            float4 bv = *(const float4*)&Bs[kk][tx * 4];
            float a_[4] = {av.x, av.y, av.z, av.w};
            float b_[4] = {bv.x, bv.y, bv.z, bv.w};
#pragma unroll
            for (int i = 0; i < 4; ++i)
#pragma unroll
                for (int j = 0; j < 4; ++j)
                    acc[i][j] = fmaf(a_[i], b_[j], acc[i][j]);
        }
        __syncthreads();
    }
    float4 bv = *(const float4*)(bias + col0 + tx * 4);
    float bb[4] = {bv.x, bv.y, bv.z, bv.w};
#pragma unroll
    for (int i = 0; i < 4; ++i) {
        float4 o;
        o.x = fmaxf(acc[i][0] + bb[0], 0.f);
        o.y = fmaxf(acc[i][1] + bb[1], 0.f);
        o.z = fmaxf(acc[i][2] + bb[2], 0.f);
        o.w = fmaxf(acc[i][3] + bb[3], 0.f);
        *(float4*)(C + (size_t)(row0 + ty * 4 + i) * N + col0 + tx * 4) = o;
    }
}

// ---------------- weight prep: transpose + split ----------------------------
__global__ __launch_bounds__(256) void prep_wt(
    const float* __restrict__ w, ushort_t* __restrict__ th,
    ushort_t* __restrict__ tl, int K, int N)
{
    int idx = blockIdx.x * 256 + threadIdx.x;   // n*K + k
    int n = idx / K, k = idx % K;
    float v = w[(size_t)k * N + n];
    split2(v, th[idx], tl[idx]);
}

// ---------------- init: io = inp + out_e ; xs = split(io + lat_e) -----------
__global__ __launch_bounds__(256) void init_xs(
    const float* __restrict__ inpf, const float* __restrict__ oute,
    const float* __restrict__ late, float* __restrict__ io,
    ushort_t* __restrict__ xh, ushort_t* __restrict__ xl)
{
    int i = blockIdx.x * 256 + threadIdx.x;     // 1024*512
    float t = inpf[i] + oute[i];
    io[i] = t;
    split2(t + late[i], xh[i], xl[i]);
}

// ---------------- barrier init ---------------------------------------------
__global__ void init_bar(unsigned* bar) {
    bar[threadIdx.x] = 0;          // [0..255]: group barrier counters (g*32)
    bar[threadIdx.x + 256] = 0;    // [384+x*8]: XCD slot-claim counters
}

// ---------------------------------------------------------------------------
// Per-XCD-group (32-block) barrier — r7 structure verbatim (proven fastest).
// ---------------------------------------------------------------------------
__device__ __forceinline__ void group_barrier(unsigned* bar, int g,
                                              unsigned& tgt)
{
    __syncthreads();
    if (threadIdx.x == 0) {
        __builtin_amdgcn_fence(__ATOMIC_RELEASE, "workgroup");
        __hip_atomic_fetch_add(bar + g * 32, 1u, __ATOMIC_RELAXED,
                               __HIP_MEMORY_SCOPE_AGENT);
        while (__hip_atomic_load(bar + g * 32, __ATOMIC_RELAXED,
                                 __HIP_MEMORY_SCOPE_AGENT) < tgt)
            __builtin_amdgcn_s_sleep(1);
        __builtin_amdgcn_fence(__ATOMIC_ACQUIRE, "workgroup");
        asm volatile("buffer_inv sc0" ::: "memory");   // vector L1 inv only
    }
    tgt += 32;
    __syncthreads();
}

// A-operand fragment load from global (MFMA 16x16x32 A layout:
// lane (li,q) holds A[row][q*8..q*8+8) at kpos offset).
__device__ __forceinline__ short8 afrag(const ushort_t* __restrict__ p,
                                        int row, int K, int kpos)
{
    return *(const short8*)(p + (size_t)row * K + kpos);
}

// ---------------------------------------------------------------------------
// Persistent TRM kernel. grid 256, 1024 threads (16 waves, 4/SIMD), 1 blk/CU
// (136KB LDS). __launch_bounds__(1024,1) -> VGPR cap 128, NO spills (the r12
// failure mode). Block self-assigns (g = physical XCD, slot = claim 0..31).
// Group g owns rows [g*128, g*128+128). Wave pair (w, w+8), w in [0,8),
// shares row tile rowA = g*128 + w*16:
//   GEMM1 (N-split): lo wave cols [c1,c1+16), hi wave [c1+16,c1+32), full K.
//   GEMM2 (K-split): lo K [0,512), hi K [512,1024); hi -> LDS scr;
//                    __syncthreads; lo adds + runs recursion epilogue.
// LDS weights in MFMA fragment order: every ds_read_b128 wave-contiguous 1KB.
// A-prefetch: ring-2, consume-then-prefetch, NO pins (TLP is the cover).
// ---------------------------------------------------------------------------
__global__ __launch_bounds__(1024, 1) void trm_persist(
    ushort_t* __restrict__ xs_hi, ushort_t* __restrict__ xs_lo,
    ushort_t* __restrict__ h1_hi, ushort_t* __restrict__ h1_lo,
    const ushort_t* __restrict__ W1h, const ushort_t* __restrict__ W1l,
    const ushort_t* __restrict__ W2h, const ushort_t* __restrict__ W2l,
    const float* __restrict__ bb1, const float* __restrict__ bb2,
    float* __restrict__ io, const float* __restrict__ inpf,
    float* __restrict__ latf, float* __restrict__ outf,
    const float* __restrict__ hw, const float* __restrict__ hb,
    float* __restrict__ logits, unsigned* bar)
{
    __shared__ __align__(16) unsigned char w1lds[65536];
    __shared__ __align__(16) unsigned char w2lds[65536];
    __shared__ __align__(16) f32x4 scr[512];     // 8KB GEMM2 partial exchange
    __shared__ int sh_gs;

    const int tid = threadIdx.x;
    const int w = tid >> 6, lane = tid & 63;
    const int q = lane >> 4, li = lane & 15;
    const int rw = w & 7;                 // row-tile index (pairs share)
    const int hi_half = w >> 3;           // 0 = lo wave, 1 = hi wave

    // ---- self-organize: group by PHYSICAL XCD, claim slot ----
    if (tid == 0) {
        unsigned xcc;
        asm volatile("s_getreg_b32 %0, hwreg(HW_REG_XCC_ID)" : "=s"(xcc));
        xcc &= 7u;
        unsigned s = __hip_atomic_fetch_add(bar + 384 + xcc * 8, 1u,
                                            __ATOMIC_RELAXED,
                                            __HIP_MEMORY_SCOPE_AGENT);
        sh_gs = (int)((xcc << 8) | (s & 31u));
    }
    __syncthreads();
    const int g = sh_gs >> 8;
    const int slot = sh_gs & 255;
    const int c1 = slot * 32;       // GEMM1 col base
    const int c2 = slot * 16;       // GEMM2 col base
    const int rowA = g * 128 + rw * 16;

    // ---- preload weight slices into LDS in fragment order (once) ----
    for (int i = tid; i < 4096; i += 1024) {              // W1: 2*32n*64c
        int comp = i >> 11;
        int rem = i & 2047;
        int n = rem >> 6, c = rem & 63;                   // n 0..31, c 0..63
        const ushort_t* src = (comp ? W1l : W1h) + (size_t)(c1 + n) * 512 + c * 8;
        int dst = ((((comp << 4) + (c >> 2)) * 2 + (n >> 4)) * 64 +
                   ((c & 3) * 16 + (n & 15))) * 16;
        *(uint4*)(w1lds + dst) = *(const uint4*)src;
    }
    for (int i = tid; i < 4096; i += 1024) {              // W2: 2*16n*128c
        int comp = i >> 11;
        int rem = i & 2047;
        int n = rem >> 7, c = rem & 127;                  // n 0..15, c 0..127
        const ushort_t* src = (comp ? W2l : W2h) + (size_t)(c2 + n) * 1024 + c * 8;
        int dst = (((comp << 5) + (c >> 2)) * 64 + ((c & 3) * 16 + n)) * 16;
        *(uint4*)(w2lds + dst) = *(const uint4*)src;
    }
    __syncthreads();

    // per-wave GEMM1 bias (its own 16-col tile) and GEMM2 bias (lo only)
    float bias1v = bb1[c1 + hi_half * 16 + li];
    float bias2 = bb2[c2 + li];
    unsigned tgt = 32;

    for (int step = 0; step < 336; ++step) {              // 48 sup * 7
        // ==== GEMM1: h1[16r x 32c] = relu(xs @ W1 + bb1); N-split pair ====
        {
            f32x4 acc = {};
            short8 aF[2][2];                              // ring-2 [slot][comp]
#pragma unroll
            for (int p = 0; p < 2; ++p) {
                int kp = p * 32 + q * 8;
                aF[p][0] = afrag(xs_hi, rowA + li, 512, kp);
                aF[p][1] = afrag(xs_lo, rowA + li, 512, kp);
            }
            const int tjoff = hi_half * 1024;             // B-tile byte offset
#pragma unroll
            for (int s = 0; s < 16; ++s) {
                short8 ah = aF[s & 1][0], al = aF[s & 1][1];   // consume first
                if (s + 2 < 16) {
                    int kp = (s + 2) * 32 + q * 8;
                    aF[s & 1][0] = afrag(xs_hi, rowA + li, 512, kp);
                    aF[s & 1][1] = afrag(xs_lo, rowA + li, 512, kp);
                }
                const int base = (s * 2 * 64 + lane) * 16 + tjoff;
                short8 bh = *(const short8*)(w1lds + base);
                short8 bl = *(const short8*)(w1lds + 32768 + base);
                acc = __builtin_amdgcn_mfma_f32_16x16x32_bf16(ah, bh, acc, 0, 0, 0);
                acc = __builtin_amdgcn_mfma_f32_16x16x32_bf16(ah, bl, acc, 0, 0, 0);
                acc = __builtin_amdgcn_mfma_f32_16x16x32_bf16(al, bh, acc, 0, 0, 0);
                acc = __builtin_amdgcn_mfma_f32_16x16x32_bf16(al, bl, acc, 0, 0, 0);
            }
            // epilogue: each wave writes its own 16-col tile
            int colg = c1 + hi_half * 16 + li;
#pragma unroll
            for (int rr = 0; rr < 4; ++rr) {
                int rowg = rowA + q * 4 + rr;
                size_t idx = (size_t)rowg * 1024 + colg;
                float v = fmaxf(acc[rr] + bias1v, 0.f);
                split2(v, h1_hi[idx], h1_lo[idx]);
            }
        }
        group_barrier(bar, g, tgt);

        // ==== GEMM2: xs'[16r x 16c] = f(relu(h1 @ W2 + bb2)); K-split ====
        {
            int im = step % 7;
            int mode = (im < 5) ? 1 : ((im == 5) ? 2 : 3);
            f32x4 acc = {};
            short8 aF[2][2];
            const int sb = hi_half * 16;                  // K-half s-base
#pragma unroll
            for (int p = 0; p < 2; ++p) {
                int kp = (sb + p) * 32 + q * 8;
                aF[p][0] = afrag(h1_hi, rowA + li, 1024, kp);
                aF[p][1] = afrag(h1_lo, rowA + li, 1024, kp);
            }
#pragma unroll
            for (int s = 0; s < 16; ++s) {
                short8 ah = aF[s & 1][0], al = aF[s & 1][1];   // consume first
                if (s + 2 < 16) {
                    int kp = (sb + s + 2) * 32 + q * 8;
                    aF[s & 1][0] = afrag(h1_hi, rowA + li, 1024, kp);
                    aF[s & 1][1] = afrag(h1_lo, rowA + li, 1024, kp);
                }
                const int base = ((sb + s) * 64 + lane) * 16;
                short8 bh = *(const short8*)(w2lds + base);
                short8 bl = *(const short8*)(w2lds + 32768 + base);
                acc = __builtin_amdgcn_mfma_f32_16x16x32_bf16(ah, bh, acc, 0, 0, 0);
                acc = __builtin_amdgcn_mfma_f32_16x16x32_bf16(ah, bl, acc, 0, 0, 0);
                acc = __builtin_amdgcn_mfma_f32_16x16x32_bf16(al, bh, acc, 0, 0, 0);
                acc = __builtin_amdgcn_mfma_f32_16x16x32_bf16(al, bl, acc, 0, 0, 0);
            }
            // K-split reduction: hi half deposits partial, lo half finishes
            if (hi_half) scr[rw * 64 + lane] = acc;
            __syncthreads();
            if (!hi_half) {
                acc += scr[rw * 64 + lane];
                int colg = c2 + li;
#pragma unroll
                for (int rr = 0; rr < 4; ++rr) {
                    int rowg = rowA + q * 4 + rr;
                    size_t idx = (size_t)rowg * 512 + colg;
                    float v = fmaxf(acc[rr] + bias2, 0.f);
                    if (mode == 1) {
                        split2(io[idx] + v, xs_hi[idx], xs_lo[idx]);
                    } else if (mode == 2) {
                        split2(inpf[idx] + v, xs_hi[idx], xs_lo[idx]);
                        latf[idx] = v;
                    } else {
                        outf[idx] = v;
                        float t2 = inpf[idx] + v;
                        io[idx] = t2;
                        split2(t2 + latf[idx], xs_hi[idx], xs_lo[idx]);
                    }
                }
            }
        }
        group_barrier(bar, g, tgt);
    }

    // ---- head: logits rows [g*128, g*128+128), 1280 elems per group ----
    // (last loop iteration ended with a full group barrier; outf is visible)
    {
        int idx = slot * 1024 + tid;
        if (idx < 1280) {
            int rloc = idx / 10, j = idx % 10;
            int row = g * 128 + rloc;
            const float* r = outf + (size_t)row * 512;
            float s = hb[j];
            for (int k = 0; k < 512; ++k) s = fmaf(r[k], hw[k * 10 + j], s);
            logits[row * 10 + j] = s;
        }
    }
}

extern "C" void kernel_launch(void* const* d_in, const int* in_sizes, int n_in,
                              void* d_out, int out_size, void* d_ws, size_t ws_size,
                              hipStream_t stream)
{
    const float* raw   = (const float*)d_in[0];
    const float* out_e = (const float*)d_in[1];
    const float* lat_e = (const float*)d_in[2];
    const float* c1w = (const float*)d_in[3];
    const float* c1b = (const float*)d_in[4];
    const float* c2w = (const float*)d_in[5];
    const float* c2b = (const float*)d_in[6];
    const float* pw1 = (const float*)d_in[7];
    const float* pb1 = (const float*)d_in[8];
    const float* pw2 = (const float*)d_in[9];
    const float* pb2 = (const float*)d_in[10];
    const float* bw1 = (const float*)d_in[11];
    const float* bb1 = (const float*)d_in[12];
    const float* bw2 = (const float*)d_in[13];
    const float* bb2 = (const float*)d_in[14];
    const float* hw  = (const float*)d_in[15];
    const float* hb  = (const float*)d_in[16];
    // d_in[17]=Nsup(16), d_in[18]=n_latent(6): fixed, hard-coded.

    char* base = (char*)d_ws;
    float*    pool1  = (float*)   (base + 0);          // conv1 out (pre-backbone)
    ushort_t* h1_hi  = (ushort_t*)(base + 0);
    ushort_t* h1_lo  = (ushort_t*)(base + 2097152);
    ushort_t* xs_hi  = (ushort_t*)(base + 4194304);
    ushort_t* xs_lo  = (ushort_t*)(base + 5242880);
    float*    io     = (float*)   (base + 6291456);
    float*    latf   = (float*)   (base + 8388608);
    float*    h1f    = (float*)   (base + 0);          // proj1 out (pre-backbone)
    float*    h      = (float*)   (base + 12845056);   // conv2 out fp32
    float*    inpf   = (float*)   (base + 19267584);
    float*    outf   = (float*)   (base + 21364736);
    ushort_t* bW1t_h = (ushort_t*)(base + 23461888);   // [1024n][512k]
    ushort_t* bW1t_l = (ushort_t*)(base + 24510464);
    ushort_t* bW2t_h = (ushort_t*)(base + 25559040);   // [512n][1024k]
    ushort_t* bW2t_l = (ushort_t*)(base + 26607616);
    unsigned* bar    = (unsigned*)(base + 27656192);   // 2KB barrier/claim

    // weight prep (every launch; ws is re-poisoned by harness)
    prep_wt<<<2048, 256, 0, stream>>>(bw1, bW1t_h, bW1t_l, 512, 1024);
    prep_wt<<<2048, 256, 0, stream>>>(bw2, bW2t_h, bW2t_l, 1024, 512);

    // fp32 prologue
    conv1_pool<<<3211264 / 256, 256, 0, stream>>>(raw, c1w, c1b, pool1);
    conv2_pool<<<1605632 / 256, 256, 0, stream>>>(pool1, c2w, c2b, h);
    gemm_f32<<<dim3(16, 16), 256, 0, stream>>>(h, pw1, pb1, h1f, 1024, 1024, 1568);
    gemm_f32<<<dim3(8, 16), 256, 0, stream>>>(h1f, pw2, pb2, inpf, 1024, 512, 1024);
    init_xs<<<2048, 256, 0, stream>>>(inpf, out_e, lat_e, io, xs_hi, xs_lo);

    // barrier init (bar region untouched by the prologue; launched last)
    init_bar<<<1, 256, 0, stream>>>(bar);

    // the whole recursion + head in ONE persistent kernel
    trm_persist<<<256, 1024, 0, stream>>>(
        xs_hi, xs_lo, h1_hi, h1_lo, bW1t_h, bW1t_l, bW2t_h, bW2t_l,
        bb1, bb2, io, inpf, latf, outf, hw, hb, (float*)d_out, bar);
}